// Round 12
// baseline (257.882 us; speedup 1.0000x reference)
//
#include <hip/hip_runtime.h>
#include <hip/hip_bf16.h>

// Problem constants (from reference)
#define BB    16
#define LQ    64
#define LD    2048
#define HH    1024
#define DIM   128
#define MAXK  513          // LD/PF + 1 with PF=4
#define SCH   9            // ceil(513/64) cluster chunks for simmax

typedef __attribute__((ext_vector_type(8))) short short8;
typedef __attribute__((ext_vector_type(4))) float f32x4;

__device__ __forceinline__ float b2f(ushort u) {
    union { float f; unsigned int u32; } c; c.u32 = ((unsigned int)u) << 16; return c.f;
}
__device__ __forceinline__ ushort f2b_rn(float f) {
    unsigned int x = __float_as_uint(f);
    return (ushort)((x + 0x7fffu + ((x >> 16) & 1u)) >> 16);
}

// async global->LDS, 16B/lane; LDS dest = wave-uniform base + lane*16,
// global src is PER-LANE. No dest VGPR -> counted-vmcnt pipelining of these
// is SOUND (unlike r10's asm reg-ring, where the compiler realloc'd in-flight
// dest regs -> absmax 1.5e5).
__device__ __forceinline__ void gld16(void* lds, const void* g) {
    __builtin_amdgcn_global_load_lds(
        (const __attribute__((address_space(1))) unsigned int*)g,
        (__attribute__((address_space(3))) unsigned int*)lds,
        16, 0, 0);
}

// ---------------------------------------------------------------------------
// Fused prep (r3-proven):
//   blocks [0,16):   LDS-tile transpose+round W -> Wt bf16 (coalesced writes)
//   blocks [16,32):  kvals per batch
//   blocks [32,288): zero sums
__global__ __launch_bounds__(256) void prep_kb_kernel(
    const float* __restrict__ W,
    const int*   __restrict__ d_mask,
    const int*   __restrict__ pf,
    ushort*      __restrict__ Wt,
    int*         __restrict__ kvals,
    float*       __restrict__ sums)
{
    int bid = blockIdx.x, t = threadIdx.x;
    if (bid < 16) {
        __shared__ ushort tile[128][72];   // stride 72 ushorts = 144B
        const int h0 = bid * 64;
        #pragma unroll
        for (int i = 0; i < 32; ++i) {     // 64*128/256
            int flat = i * 256 + t;
            int r = flat >> 7, c = flat & 127;
            tile[c][r] = f2b_rn(W[(long)(h0 + r) * DIM + c]);
        }
        __syncthreads();
        #pragma unroll
        for (int i = 0; i < 4; ++i) {      // 128 rows x 8 uint4 = 1024 uint4
            int flat = i * 256 + t;
            int n = flat >> 3, u = flat & 7;
            uint4 v = *(const uint4*)&tile[n][u * 8];
            *(uint4*)&Wt[(long)n * HH + h0 + u * 8] = v;
        }
    } else if (bid < 32) {
        __shared__ int red[4];
        int b = bid - 16;
        int lane = t & 63, wave = t >> 6;
        int s = 0;
        for (int i = t; i < LD; i += 256) s += (d_mask[b * LD + i] > 0) ? 1 : 0;
        #pragma unroll
        for (int m = 1; m < 64; m <<= 1) s += __shfl_xor(s, m);
        if (lane == 0) red[wave] = s;
        __syncthreads();
        if (t == 0) {
            int v = red[0] + red[1] + red[2] + red[3];
            if (v < 2) v = 2;
            int pfv = pf[0];
            if (pfv < 1 || pfv > LD) pfv = 4;   // defensive
            kvals[b] = v / pfv + 1;
        }
    } else {
        const int total4 = (BB * MAXK * DIM) / 4;
        float4* s4 = (float4*)sums;
        const float4 z = make_float4(0.f, 0.f, 0.f, 0.f);
        for (int i = (bid - 32) * 256 + t; i < total4; i += 256 * 256)
            s4[i] = z;
    }
}

// ---------------------------------------------------------------------------
// Encode (W-stationary, single bf16 pass, double-buffered counted-vmcnt):
//   <<<16,256>>>  isq=1 : q rows (64 units)
//   <<<512,256>>> isq=0 : d rows (2048 units) + fused pooled-scatter
// 4 waves/block, wave = one 16-row unit x all 128 cols. LDS 64 KB = 2 buffers
// x 2048 u4 units:
//   buf b: W sixteenth [n=128][u'=8] at [b*2048, +1024) (XOR-swz source),
//          A 2 chunk-slots/wave [16r][8u] at [b*2048+1024 + w*256, +256)
// 16 half-phases x 2 chunks. Per half-phase per wave: 8 gld16 (4 W + 4 A).
// Pipeline (T3/T4 on the r11-proven structure -- r11 drained vmcnt(0) at
// every phase, exposing full HBM latency 8x):
//   prologue: issue hp0->buf0, hp1->buf1          [16 outstanding]
//   iter i (0..14): vmcnt(8) [buf i&1 landed, other buf in flight];
//     s_barrier; compute 2 chunks; s_barrier [all waves done reading W];
//     issue hp i+2 into buf i&1  (skip when i+2>15)
//   iter 15: vmcnt(0); s_barrier; compute.
// Identical math/swizzles to r11 -> correctness isolates the schedule.
__global__ __launch_bounds__(256, 2) void encode_kernel(
    const float*  __restrict__ X,       // [nrows][H]
    const ushort* __restrict__ Wt,      // [DIM][H] bf16 rounded
    const float*  __restrict__ bias,    // [DIM]
    const int*    __restrict__ mask,    // [nrows]
    const int*    __restrict__ labels,  // [32768] (d only)
    const int*    __restrict__ kvals,   // [BB]    (d only)
    float*        __restrict__ sums,    // [BB][MAXK][DIM] (d only)
    float*        __restrict__ q_repr,  // [1024][DIM]     (q only)
    int           isq)
{
    __shared__ __align__(16) uint4 lds[4096];    // 64 KB

    const int t = threadIdx.x;
    const int w = t >> 6, lane = t & 63;
    const int m16 = lane & 15, quad = lane >> 4;

    const int unit = blockIdx.x * 4 + w;
    const long row0 = (long)unit * 16;

    f32x4 acc[8];
    #pragma unroll
    for (int j = 0; j < 8; ++j) acc[j] = (f32x4){0.f, 0.f, 0.f, 0.f};

    const int sw8 = m16 & 7;

    // A staging source (r0-proven swizzle): lane l -> row (l>>3),
    // k-part ((l&7)^((l>>3)&7))*4 floats (+ chunk*32); rows 8-15 via +8*HH.
    const float* gA = X + (row0 + (lane >> 3)) * HH
                        + (((lane & 7) ^ ((lane >> 3) & 7)) * 4);

    // stage half-phase hp into buffer b (8 gld16/wave, wave-uniform LDS dests)
    auto stage = [&](int b, int hp) {
        const int bofs = b * 2048;
        #pragma unroll
        for (int i = 0; i < 4; ++i) {              // W: 256 units/wave
            int Si = w * 256 + i * 64 + lane;      // slot in [0,1024)
            int n = Si >> 3, up = Si & 7;
            const ushort* src = Wt + (long)n * HH + (hp * 8 + (up ^ (n & 7))) * 8;
            gld16(&lds[bofs + w * 256 + i * 64], src);
        }
        #pragma unroll
        for (int s = 0; s < 2; ++s) {              // A: 2 chunk-slots/wave
            const long ko = (long)(hp * 2 + s) * 32;
            gld16(&lds[bofs + 1024 + w * 256 + s * 128], gA + ko);
            gld16(&lds[bofs + 1024 + w * 256 + s * 128 + 64], gA + 8 * HH + ko);
        }
    };

    auto compute = [&](int b) {
        const ushort* Wu = (const ushort*)&lds[b * 2048];
        const float4* Af = (const float4*)&lds[b * 2048 + 1024 + w * 256];
        #pragma unroll
        for (int cc = 0; cc < 2; ++cc) {
            float4 va0 = Af[cc * 128 + m16 * 8 + ((2 * quad) ^ sw8)];
            float4 va1 = Af[cc * 128 + m16 * 8 + ((2 * quad + 1) ^ sw8)];
            float av[8];
            *(float4*)(av)     = va0;
            *(float4*)(av + 4) = va1;
            short8 ah;
            #pragma unroll
            for (int j = 0; j < 8; ++j) ah[j] = (short)f2b_rn(av[j]);
            #pragma unroll
            for (int ct = 0; ct < 8; ++ct) {
                short8 bf = *(const short8*)
                    &Wu[((ct * 16 + m16) * 8 + ((cc * 4 + quad) ^ sw8)) * 8];
                acc[ct] = __builtin_amdgcn_mfma_f32_16x16x32_bf16(ah, bf, acc[ct], 0, 0, 0);
            }
        }
    };

    // prologue: two half-phases in flight
    stage(0, 0);
    stage(1, 1);

    for (int i = 0; i < 15; ++i) {
        asm volatile("s_waitcnt vmcnt(8)" ::: "memory");   // buf i&1 landed
        __builtin_amdgcn_s_barrier();
        __builtin_amdgcn_sched_barrier(0);
        compute(i & 1);
        __builtin_amdgcn_s_barrier();                      // all done reading
        __builtin_amdgcn_sched_barrier(0);
        if (i + 2 < 16) stage(i & 1, i + 2);
    }
    asm volatile("s_waitcnt vmcnt(0)" ::: "memory");       // last buffer
    __builtin_amdgcn_s_barrier();
    __builtin_amdgcn_sched_barrier(0);
    compute(1);

    // epilogue: bias, in-wave row norm, mask, store/scatter (r11-proven)
    float bia[8];
    #pragma unroll
    for (int ct = 0; ct < 8; ++ct) bia[ct] = bias[ct * 16 + m16];

    float vv[8][4];
    float ssp[4] = {0.f, 0.f, 0.f, 0.f};
    #pragma unroll
    for (int ct = 0; ct < 8; ++ct)
        #pragma unroll
        for (int r = 0; r < 4; ++r) {
            vv[ct][r] = acc[ct][r] + bia[ct];
            ssp[r] += vv[ct][r] * vv[ct][r];
        }
    #pragma unroll
    for (int r = 0; r < 4; ++r) {
        ssp[r] += __shfl_xor(ssp[r], 1);
        ssp[r] += __shfl_xor(ssp[r], 2);
        ssp[r] += __shfl_xor(ssp[r], 4);
        ssp[r] += __shfl_xor(ssp[r], 8);
    }

    #pragma unroll
    for (int r = 0; r < 4; ++r) {
        long rowg = row0 + quad * 4 + r;
        float scale = 1.0f / fmaxf(sqrtf(ssp[r]), 1e-12f);
        if (isq) {
            scale *= (float)mask[rowg];
            #pragma unroll
            for (int ct = 0; ct < 8; ++ct)
                q_repr[rowg * DIM + ct * 16 + m16] = vv[ct][r] * scale;
        } else if (mask[rowg] > 0) {
            int b = (int)(rowg >> 11);
            int seg = labels[rowg] % kvals[b];
            float* sp = sums + ((long)b * MAXK + seg) * DIM + m16;
            #pragma unroll
            for (int ct = 0; ct < 8; ++ct)
                atomicAdd(sp + ct * 16, vv[ct][r] * scale);
        }
    }
}

// ---------------------------------------------------------------------------
// Sim via MFMA (r3-proven, hi/lo Q kept for precision): block = (b, 64-cluster
// chunk). Stage Q (split bf16) and C (rounded bf16) in LDS, MFMA over K=128,
// per-cluster rsqrt, shuffle-max -> pmax[b][chunk][64].
__global__ __launch_bounds__(256) void simmax_kernel(
    const float* __restrict__ q_repr,   // [B][LQ][DIM]
    const float* __restrict__ sums,     // [B][MAXK][DIM] raw cluster sums
    const int*   __restrict__ kvals,
    float*       __restrict__ pmax)     // [B][SCH][64]
{
    __shared__ __align__(16) ushort Qh[64 * 136];
    __shared__ __align__(16) ushort Ql[64 * 136];
    __shared__ __align__(16) ushort Ch[64 * 136];
    __shared__ float cn[64];

    int b = blockIdx.x / SCH, chunk = blockIdx.x % SCH;
    int t = threadIdx.x, w = t >> 6, lane = t & 63;
    int m16 = lane & 15, quad = lane >> 4;

    #pragma unroll
    for (int i = 0; i < 8; ++i) {
        int flat = i * 256 + t;          // float4 index
        int row = flat >> 5, c4 = flat & 31;
        float4 v = *(const float4*)(q_repr + ((long)b * LQ + row) * DIM + c4 * 4);
        float x[4]; *(float4*)x = v;
        ushort4 h, l;
        ushort* hp = (ushort*)&h; ushort* lp = (ushort*)&l;
        #pragma unroll
        for (int j = 0; j < 4; ++j) {
            unsigned int ux = __float_as_uint(x[j]);
            hp[j] = (ushort)(ux >> 16);
            lp[j] = f2b_rn(x[j] - __uint_as_float(ux & 0xffff0000u));
        }
        *(ushort4*)&Qh[row * 136 + c4 * 4] = h;
        *(ushort4*)&Ql[row * 136 + c4 * 4] = l;
    }
    #pragma unroll
    for (int i = 0; i < 8; ++i) {
        int flat = i * 256 + t;
        int row = flat >> 5, c4 = flat & 31;
        int kk = chunk * 64 + row;
        float4 v = (kk < MAXK)
            ? *(const float4*)(sums + ((long)b * MAXK + kk) * DIM + c4 * 4)
            : make_float4(0.f, 0.f, 0.f, 0.f);
        ushort4 h; ushort* hp = (ushort*)&h;
        hp[0] = f2b_rn(v.x); hp[1] = f2b_rn(v.y);
        hp[2] = f2b_rn(v.z); hp[3] = f2b_rn(v.w);
        *(ushort4*)&Ch[row * 136 + c4 * 4] = h;
    }
    __syncthreads();

    {
        int c = w * 16 + m16;
        float ssv = 0.f;
        #pragma unroll
        for (int j = 0; j < 16; ++j) {
            unsigned int u = *(const unsigned int*)&Ch[c * 136 + quad * 32 + j * 2];
            float x0 = b2f((ushort)u), x1 = b2f((ushort)(u >> 16));
            ssv += x0 * x0 + x1 * x1;
        }
        ssv += __shfl_xor(ssv, 16);
        ssv += __shfl_xor(ssv, 32);
        if (quad == 0) cn[c] = (ssv > 1e-24f) ? rsqrtf(ssv) : 0.f;
    }
    __syncthreads();

    f32x4 acc[4];
    #pragma unroll
    for (int j = 0; j < 4; ++j) acc[j] = (f32x4){0.f, 0.f, 0.f, 0.f};

    #pragma unroll
    for (int kc = 0; kc < 4; ++kc) {
        short8 qh = *(const short8*)&Qh[(w * 16 + m16) * 136 + kc * 32 + quad * 8];
        short8 ql = *(const short8*)&Ql[(w * 16 + m16) * 136 + kc * 32 + quad * 8];
        #pragma unroll
        for (int ct = 0; ct < 4; ++ct) {
            short8 cf = *(const short8*)&Ch[(ct * 16 + m16) * 136 + kc * 32 + quad * 8];
            acc[ct] = __builtin_amdgcn_mfma_f32_16x16x32_bf16(qh, cf, acc[ct], 0, 0, 0);
            acc[ct] = __builtin_amdgcn_mfma_f32_16x16x32_bf16(ql, cf, acc[ct], 0, 0, 0);
        }
    }

    int kb = kvals[b];
    #pragma unroll
    for (int r = 0; r < 4; ++r) {
        float mx = -1e4f;
        #pragma unroll
        for (int ct = 0; ct < 4; ++ct) {
            int cl = chunk * 64 + ct * 16 + m16;
            float sim = acc[ct][r] * cn[ct * 16 + m16];
            mx = fmaxf(mx, (cl < kb) ? sim : -1e4f);
        }
        mx = fmaxf(mx, __shfl_xor(mx, 1));
        mx = fmaxf(mx, __shfl_xor(mx, 2));
        mx = fmaxf(mx, __shfl_xor(mx, 4));
        mx = fmaxf(mx, __shfl_xor(mx, 8));
        if (m16 == 0)
            pmax[((long)b * SCH + chunk) * 64 + w * 16 + quad * 4 + r] = mx;
    }
}

// ---------------------------------------------------------------------------
// Final: per batch, max over chunks, *q_mask, sum over rows -> out[b]
__global__ __launch_bounds__(64) void final_kernel(
    const float* __restrict__ pmax,
    const int*   __restrict__ q_mask,
    float*       __restrict__ out)
{
    int b = blockIdx.x, r = threadIdx.x;
    float m = -3e38f;
    #pragma unroll
    for (int c = 0; c < SCH; ++c)
        m = fmaxf(m, pmax[((long)b * SCH + c) * 64 + r]);
    m *= (float)q_mask[b * LQ + r];
    #pragma unroll
    for (int sh = 1; sh < 64; sh <<= 1) m += __shfl_xor(m, sh);
    if (r == 0) out[b] = m;
}

// ---------------------------------------------------------------------------
extern "C" void kernel_launch(void* const* d_in, const int* in_sizes, int n_in,
                              void* d_out, int out_size, void* d_ws, size_t ws_size,
                              hipStream_t stream) {
    const float* q_hidden = (const float*)d_in[0];
    const float* d_hidden = (const float*)d_in[1];
    const float* W        = (const float*)d_in[2];
    const float* bias     = (const float*)d_in[3];
    const int*   q_mask   = (const int*)d_in[4];
    const int*   d_mask   = (const int*)d_in[5];
    const int*   labels   = (const int*)d_in[6];
    const int*   pf       = (const int*)d_in[7];

    float* ws     = (float*)d_ws;
    float* q_repr = ws;                                   // 131,072 f
    float* sums   = q_repr + (long)BB * LQ * DIM;         // 1,050,624 f
    float* pmaxb  = sums + (long)BB * MAXK * DIM;         // 16*9*64 = 9,216 f
    int*   kvals  = (int*)(pmaxb + BB * SCH * 64);        // 16
    ushort* Wt    = (ushort*)(kvals + 16);                // 131,072 bf16

    prep_kb_kernel<<<288, 256, 0, stream>>>(W, d_mask, pf, Wt, kvals, sums);
    // q first (16 blocks, warms Wt in L2), then d (512 blocks, 2/CU)
    encode_kernel<<<16, 256, 0, stream>>>(q_hidden, Wt, bias, q_mask,
                                          labels, kvals, sums, q_repr, 1);
    encode_kernel<<<512, 256, 0, stream>>>(d_hidden, Wt, bias, d_mask,
                                           labels, kvals, sums, q_repr, 0);
    simmax_kernel<<<BB * SCH, 256, 0, stream>>>(q_repr, sums, kvals, pmaxb);
    final_kernel<<<BB, 64, 0, stream>>>(pmaxb, q_mask, (float*)d_out);
}

// Round 13
// 248.834 us; speedup vs baseline: 1.0364x; 1.0364x over previous
//
#include <hip/hip_runtime.h>
#include <hip/hip_bf16.h>

// Problem constants (from reference)
#define BB    16
#define LQ    64
#define LD    2048
#define HH    1024
#define DIM   128
#define MAXK  513          // LD/PF + 1 with PF=4
#define SCH   9            // ceil(513/64) cluster chunks for simmax

typedef __attribute__((ext_vector_type(8))) short short8;
typedef __attribute__((ext_vector_type(4))) float f32x4;

__device__ __forceinline__ float b2f(ushort u) {
    union { float f; unsigned int u32; } c; c.u32 = ((unsigned int)u) << 16; return c.f;
}
__device__ __forceinline__ ushort f2b_rn(float f) {
    unsigned int x = __float_as_uint(f);
    return (ushort)((x + 0x7fffu + ((x >> 16) & 1u)) >> 16);
}

// async global->LDS, 16B/lane; LDS dest = wave-uniform base + lane*16,
// global src is PER-LANE. Counted-vmcnt pipelining of these is sound
// (no dest VGPR; r10's asm reg-ring was not).
__device__ __forceinline__ void gld16(void* lds, const void* g) {
    __builtin_amdgcn_global_load_lds(
        (const __attribute__((address_space(1))) unsigned int*)g,
        (__attribute__((address_space(3))) unsigned int*)lds,
        16, 0, 0);
}

// ---------------------------------------------------------------------------
// Fused prep (r3-proven):
//   blocks [0,16):   LDS-tile transpose+round W -> Wt bf16 (coalesced writes)
//   blocks [16,32):  kvals per batch
//   blocks [32,288): zero sums
__global__ __launch_bounds__(256) void prep_kb_kernel(
    const float* __restrict__ W,
    const int*   __restrict__ d_mask,
    const int*   __restrict__ pf,
    ushort*      __restrict__ Wt,
    int*         __restrict__ kvals,
    float*       __restrict__ sums)
{
    int bid = blockIdx.x, t = threadIdx.x;
    if (bid < 16) {
        __shared__ ushort tile[128][72];   // stride 72 ushorts = 144B
        const int h0 = bid * 64;
        #pragma unroll
        for (int i = 0; i < 32; ++i) {     // 64*128/256
            int flat = i * 256 + t;
            int r = flat >> 7, c = flat & 127;
            tile[c][r] = f2b_rn(W[(long)(h0 + r) * DIM + c]);
        }
        __syncthreads();
        #pragma unroll
        for (int i = 0; i < 4; ++i) {      // 128 rows x 8 uint4 = 1024 uint4
            int flat = i * 256 + t;
            int n = flat >> 3, u = flat & 7;
            uint4 v = *(const uint4*)&tile[n][u * 8];
            *(uint4*)&Wt[(long)n * HH + h0 + u * 8] = v;
        }
    } else if (bid < 32) {
        __shared__ int red[4];
        int b = bid - 16;
        int lane = t & 63, wave = t >> 6;
        int s = 0;
        for (int i = t; i < LD; i += 256) s += (d_mask[b * LD + i] > 0) ? 1 : 0;
        #pragma unroll
        for (int m = 1; m < 64; m <<= 1) s += __shfl_xor(s, m);
        if (lane == 0) red[wave] = s;
        __syncthreads();
        if (t == 0) {
            int v = red[0] + red[1] + red[2] + red[3];
            if (v < 2) v = 2;
            int pfv = pf[0];
            if (pfv < 1 || pfv > LD) pfv = 4;   // defensive
            kvals[b] = v / pfv + 1;
        }
    } else {
        const int total4 = (BB * MAXK * DIM) / 4;
        float4* s4 = (float4*)sums;
        const float4 z = make_float4(0.f, 0.f, 0.f, 0.f);
        for (int i = (bid - 32) * 256 + t; i < total4; i += 256 * 256)
            s4[i] = z;
    }
}

// ---------------------------------------------------------------------------
// Encode, split-K x2 + fused q/d: <<<528,512>>>. 8 waves/block = 4 units x
// 2 K-halves: wave w -> unit bid*4+(w&3) (bid>=512: q units 2048+...),
// K-half g = w>>2 (k in [g*512,(g+1)*512)). 4224 waves -> 4 waves/SIMD
// (every r0-r12 variant was grid-capped at <=2/SIMD -- the diagnosed
// latency-bound residual). acc partials combined via LDS at the end.
// LDS 64 KB = 2 buffers x 2048 u4:
//   W  [b*2048, +1024): both K-halves' 32k slice, [g][n=128][u'=4],
//      u4 = g*512 + n*4 + (up ^ (n&3)), staged w/ pre-swz source
//   A  [b*2048+1024 + w*128, +128): 1 chunk [16r][8u], r0-proven swizzle
// 16 iters; per iter per wave 4 gld16 (2 W + 2 A); counted vmcnt(4),
// 2 barriers/iter (r12-proven ledger, G=4).
__global__ __launch_bounds__(512, 4) void encode_kernel(
    const float*  __restrict__ Xd,      // [32768][H]
    const float*  __restrict__ Xq,      // [1024][H]
    const ushort* __restrict__ Wt,      // [DIM][H] bf16 rounded
    const float*  __restrict__ bias,    // [DIM]
    const int*    __restrict__ mask_d,  // [32768]
    const int*    __restrict__ mask_q,  // [1024]
    const int*    __restrict__ labels,  // [32768] (d only)
    const int*    __restrict__ kvals,   // [BB]    (d only)
    float*        __restrict__ sums,    // [BB][MAXK][DIM] (d only)
    float*        __restrict__ q_repr)  // [1024][DIM]     (q only)
{
    __shared__ __align__(16) uint4 lds[4096];    // 64 KB

    const int bid = blockIdx.x, t = threadIdx.x;
    const int w = t >> 6, lane = t & 63;
    const int m16 = lane & 15, quad = lane >> 4;
    const int g = w >> 2;                        // K-half
    const int ui = w & 3;                        // unit within block

    const int unit = (bid < 512) ? (bid * 4 + ui) : (2048 + (bid - 512) * 4 + ui);
    const bool isq = unit >= 2048;
    const long row0 = isq ? (long)(unit - 2048) * 16 : (long)unit * 16;
    const float* Xb = isq ? Xq : Xd;

    // A staging source (r0-proven swizzle): lane l -> row (l>>3),
    // slot l&7 holds k-part (l&7)^((l>>3)&7); rows 8-15 via +8*HH.
    const float* gA = Xb + (row0 + (lane >> 3)) * HH
                         + (((lane & 7) ^ ((lane >> 3) & 7)) * 4);

    f32x4 acc[8];
    #pragma unroll
    for (int j = 0; j < 8; ++j) acc[j] = (f32x4){0.f, 0.f, 0.f, 0.f};

    const int sw8 = m16 & 7;

    // stage iter `it` into buffer b: 4 gld16/wave (2 W + 2 A)
    auto stage = [&](int b, int it) {
        const int bofs = b * 2048;
        #pragma unroll
        for (int i2 = 0; i2 < 2; ++i2) {           // W: slots [w*128, +128)
            int Si = w * 128 + i2 * 64 + lane;     // in [0,1024)
            int gp = Si >> 9;                      // K-half of this slot
            int n  = (Si >> 2) & 127;
            int up = Si & 3;
            const ushort* src = Wt + (long)n * HH
                              + (gp * 512 + it * 32 + (up ^ (n & 3)) * 8);
            gld16(&lds[bofs + w * 128 + i2 * 64], src);
        }
        const long koff = (long)(g * 512 + it * 32);
        gld16(&lds[bofs + 1024 + w * 128], gA + koff);
        gld16(&lds[bofs + 1024 + w * 128 + 64], gA + 8 * HH + koff);
    };

    auto compute = [&](int b) {
        const ushort* Wu = (const ushort*)&lds[b * 2048];
        const float4* Af = (const float4*)&lds[b * 2048 + 1024 + w * 128];
        float4 va0 = Af[m16 * 8 + ((2 * quad) ^ sw8)];
        float4 va1 = Af[m16 * 8 + ((2 * quad + 1) ^ sw8)];
        float av[8];
        *(float4*)(av)     = va0;
        *(float4*)(av + 4) = va1;
        short8 ah;
        #pragma unroll
        for (int j = 0; j < 8; ++j) ah[j] = (short)f2b_rn(av[j]);
        #pragma unroll
        for (int ct = 0; ct < 8; ++ct) {
            const int r = ct * 16 + m16;
            const int u4 = g * 512 + r * 4 + (quad ^ (r & 3));
            short8 bf = *(const short8*)&Wu[u4 * 8];
            acc[ct] = __builtin_amdgcn_mfma_f32_16x16x32_bf16(ah, bf, acc[ct], 0, 0, 0);
        }
    };

    // prologue: iters 0,1 in flight (8 loads/wave)
    stage(0, 0);
    stage(1, 1);

    for (int i = 0; i < 15; ++i) {
        asm volatile("s_waitcnt vmcnt(4)" ::: "memory");   // iter i landed
        __builtin_amdgcn_s_barrier();
        __builtin_amdgcn_sched_barrier(0);
        compute(i & 1);
        __builtin_amdgcn_s_barrier();                      // all done reading
        __builtin_amdgcn_sched_barrier(0);
        if (i + 2 < 16) stage(i & 1, i + 2);
    }
    asm volatile("s_waitcnt vmcnt(0)" ::: "memory");       // iter 15
    __builtin_amdgcn_s_barrier();
    __builtin_amdgcn_sched_barrier(0);
    compute(1);

    // combine K-half partials: group 1 -> LDS, group 0 adds.
    __syncthreads();                   // all computes done; buffers reusable
    if (g == 1) {
        #pragma unroll
        for (int j = 0; j < 8; ++j)
            lds[(w - 4) * 512 + j * 64 + lane] = *(const uint4*)&acc[j];
    }
    __syncthreads();
    if (g == 0) {
        #pragma unroll
        for (int j = 0; j < 8; ++j) {
            f32x4 p = *(const f32x4*)&lds[w * 512 + j * 64 + lane];
            acc[j] += p;
        }

        // epilogue (waves 0-3 only): bias, in-wave row norm, mask, store
        float bia[8];
        #pragma unroll
        for (int ct = 0; ct < 8; ++ct) bia[ct] = bias[ct * 16 + m16];

        float vv[8][4];
        float ssp[4] = {0.f, 0.f, 0.f, 0.f};
        #pragma unroll
        for (int ct = 0; ct < 8; ++ct)
            #pragma unroll
            for (int r = 0; r < 4; ++r) {
                vv[ct][r] = acc[ct][r] + bia[ct];
                ssp[r] += vv[ct][r] * vv[ct][r];
            }
        #pragma unroll
        for (int r = 0; r < 4; ++r) {
            ssp[r] += __shfl_xor(ssp[r], 1);
            ssp[r] += __shfl_xor(ssp[r], 2);
            ssp[r] += __shfl_xor(ssp[r], 4);
            ssp[r] += __shfl_xor(ssp[r], 8);
        }

        #pragma unroll
        for (int r = 0; r < 4; ++r) {
            long rowg = row0 + quad * 4 + r;
            float scale = 1.0f / fmaxf(sqrtf(ssp[r]), 1e-12f);
            if (isq) {
                scale *= (float)mask_q[rowg];
                #pragma unroll
                for (int ct = 0; ct < 8; ++ct)
                    q_repr[rowg * DIM + ct * 16 + m16] = vv[ct][r] * scale;
            } else if (mask_d[rowg] > 0) {
                int b = (int)(rowg >> 11);
                int seg = labels[rowg] % kvals[b];
                float* sp = sums + ((long)b * MAXK + seg) * DIM + m16;
                #pragma unroll
                for (int ct = 0; ct < 8; ++ct)
                    atomicAdd(sp + ct * 16, vv[ct][r] * scale);
            }
        }
    }
}

// ---------------------------------------------------------------------------
// Sim via MFMA (r3-proven, hi/lo Q kept for precision): block = (b, 64-cluster
// chunk). Stage Q (split bf16) and C (rounded bf16) in LDS, MFMA over K=128,
// per-cluster rsqrt, shuffle-max -> pmax[b][chunk][64].
__global__ __launch_bounds__(256) void simmax_kernel(
    const float* __restrict__ q_repr,   // [B][LQ][DIM]
    const float* __restrict__ sums,     // [B][MAXK][DIM] raw cluster sums
    const int*   __restrict__ kvals,
    float*       __restrict__ pmax)     // [B][SCH][64]
{
    __shared__ __align__(16) ushort Qh[64 * 136];
    __shared__ __align__(16) ushort Ql[64 * 136];
    __shared__ __align__(16) ushort Ch[64 * 136];
    __shared__ float cn[64];

    int b = blockIdx.x / SCH, chunk = blockIdx.x % SCH;
    int t = threadIdx.x, w = t >> 6, lane = t & 63;
    int m16 = lane & 15, quad = lane >> 4;

    #pragma unroll
    for (int i = 0; i < 8; ++i) {
        int flat = i * 256 + t;          // float4 index
        int row = flat >> 5, c4 = flat & 31;
        float4 v = *(const float4*)(q_repr + ((long)b * LQ + row) * DIM + c4 * 4);
        float x[4]; *(float4*)x = v;
        ushort4 h, l;
        ushort* hp = (ushort*)&h; ushort* lp = (ushort*)&l;
        #pragma unroll
        for (int j = 0; j < 4; ++j) {
            unsigned int ux = __float_as_uint(x[j]);
            hp[j] = (ushort)(ux >> 16);
            lp[j] = f2b_rn(x[j] - __uint_as_float(ux & 0xffff0000u));
        }
        *(ushort4*)&Qh[row * 136 + c4 * 4] = h;
        *(ushort4*)&Ql[row * 136 + c4 * 4] = l;
    }
    #pragma unroll
    for (int i = 0; i < 8; ++i) {
        int flat = i * 256 + t;
        int row = flat >> 5, c4 = flat & 31;
        int kk = chunk * 64 + row;
        float4 v = (kk < MAXK)
            ? *(const float4*)(sums + ((long)b * MAXK + kk) * DIM + c4 * 4)
            : make_float4(0.f, 0.f, 0.f, 0.f);
        ushort4 h; ushort* hp = (ushort*)&h;
        hp[0] = f2b_rn(v.x); hp[1] = f2b_rn(v.y);
        hp[2] = f2b_rn(v.z); hp[3] = f2b_rn(v.w);
        *(ushort4*)&Ch[row * 136 + c4 * 4] = h;
    }
    __syncthreads();

    {
        int c = w * 16 + m16;
        float ssv = 0.f;
        #pragma unroll
        for (int j = 0; j < 16; ++j) {
            unsigned int u = *(const unsigned int*)&Ch[c * 136 + quad * 32 + j * 2];
            float x0 = b2f((ushort)u), x1 = b2f((ushort)(u >> 16));
            ssv += x0 * x0 + x1 * x1;
        }
        ssv += __shfl_xor(ssv, 16);
        ssv += __shfl_xor(ssv, 32);
        if (quad == 0) cn[c] = (ssv > 1e-24f) ? rsqrtf(ssv) : 0.f;
    }
    __syncthreads();

    f32x4 acc[4];
    #pragma unroll
    for (int j = 0; j < 4; ++j) acc[j] = (f32x4){0.f, 0.f, 0.f, 0.f};

    #pragma unroll
    for (int kc = 0; kc < 4; ++kc) {
        short8 qh = *(const short8*)&Qh[(w * 16 + m16) * 136 + kc * 32 + quad * 8];
        short8 ql = *(const short8*)&Ql[(w * 16 + m16) * 136 + kc * 32 + quad * 8];
        #pragma unroll
        for (int ct = 0; ct < 4; ++ct) {
            short8 cf = *(const short8*)&Ch[(ct * 16 + m16) * 136 + kc * 32 + quad * 8];
            acc[ct] = __builtin_amdgcn_mfma_f32_16x16x32_bf16(qh, cf, acc[ct], 0, 0, 0);
            acc[ct] = __builtin_amdgcn_mfma_f32_16x16x32_bf16(ql, cf, acc[ct], 0, 0, 0);
        }
    }

    int kb = kvals[b];
    #pragma unroll
    for (int r = 0; r < 4; ++r) {
        float mx = -1e4f;
        #pragma unroll
        for (int ct = 0; ct < 4; ++ct) {
            int cl = chunk * 64 + ct * 16 + m16;
            float sim = acc[ct][r] * cn[ct * 16 + m16];
            mx = fmaxf(mx, (cl < kb) ? sim : -1e4f);
        }
        mx = fmaxf(mx, __shfl_xor(mx, 1));
        mx = fmaxf(mx, __shfl_xor(mx, 2));
        mx = fmaxf(mx, __shfl_xor(mx, 4));
        mx = fmaxf(mx, __shfl_xor(mx, 8));
        if (m16 == 0)
            pmax[((long)b * SCH + chunk) * 64 + w * 16 + quad * 4 + r] = mx;
    }
}

// ---------------------------------------------------------------------------
// Final: per batch, max over chunks, *q_mask, sum over rows -> out[b]
__global__ __launch_bounds__(64) void final_kernel(
    const float* __restrict__ pmax,
    const int*   __restrict__ q_mask,
    float*       __restrict__ out)
{
    int b = blockIdx.x, r = threadIdx.x;
    float m = -3e38f;
    #pragma unroll
    for (int c = 0; c < SCH; ++c)
        m = fmaxf(m, pmax[((long)b * SCH + c) * 64 + r]);
    m *= (float)q_mask[b * LQ + r];
    #pragma unroll
    for (int sh = 1; sh < 64; sh <<= 1) m += __shfl_xor(m, sh);
    if (r == 0) out[b] = m;
}

// ---------------------------------------------------------------------------
extern "C" void kernel_launch(void* const* d_in, const int* in_sizes, int n_in,
                              void* d_out, int out_size, void* d_ws, size_t ws_size,
                              hipStream_t stream) {
    const float* q_hidden = (const float*)d_in[0];
    const float* d_hidden = (const float*)d_in[1];
    const float* W        = (const float*)d_in[2];
    const float* bias     = (const float*)d_in[3];
    const int*   q_mask   = (const int*)d_in[4];
    const int*   d_mask   = (const int*)d_in[5];
    const int*   labels   = (const int*)d_in[6];
    const int*   pf       = (const int*)d_in[7];

    float* ws     = (float*)d_ws;
    float* q_repr = ws;                                   // 131,072 f
    float* sums   = q_repr + (long)BB * LQ * DIM;         // 1,050,624 f
    float* pmaxb  = sums + (long)BB * MAXK * DIM;         // 16*9*64 = 9,216 f
    int*   kvals  = (int*)(pmaxb + BB * SCH * 64);        // 16
    ushort* Wt    = (ushort*)(kvals + 16);                // 131,072 bf16

    prep_kb_kernel<<<288, 256, 0, stream>>>(W, d_mask, pf, Wt, kvals, sums);
    encode_kernel<<<528, 512, 0, stream>>>(d_hidden, q_hidden, Wt, bias,
                                           d_mask, q_mask, labels, kvals,
                                           sums, q_repr);
    simmax_kernel<<<BB * SCH, 256, 0, stream>>>(q_repr, sums, kvals, pmaxb);
    final_kernel<<<BB, 64, 0, stream>>>(pmaxb, q_mask, (float*)d_out);
}